// Round 1
// baseline (105.732 us; speedup 1.0000x reference)
//
#include <hip/hip_runtime.h>

// z[n, i] = m[i] + std_normal[n, i] * (diag_L[i] + JITTER)
// All f32. N = 4096, D = 16384. Pure memory-bound elementwise.

#define JITTER 1e-6f
#define D_DIM 16384

__global__ void diag_variational_kernel(const float* __restrict__ m,
                                        const float* __restrict__ diag_L,
                                        const float* __restrict__ std_normal,
                                        float* __restrict__ out,
                                        long long n4_total) {
    const int d4 = D_DIM / 4;  // float4 columns per row
    long long idx = (long long)blockIdx.x * blockDim.x + threadIdx.x;
    long long stride = (long long)gridDim.x * blockDim.x;

    const float4* sn4 = (const float4*)std_normal;
    const float4* m4 = (const float4*)m;
    const float4* dl4 = (const float4*)diag_L;
    float4* out4 = (float4*)out;

    for (long long i = idx; i < n4_total; i += stride) {
        int col = (int)(i % d4);          // column in float4 units
        float4 sn = sn4[i];
        float4 mm = m4[col];              // L2-resident broadcast
        float4 dl = dl4[col];
        float4 z;
        z.x = fmaf(sn.x, dl.x + JITTER, mm.x);
        z.y = fmaf(sn.y, dl.y + JITTER, mm.y);
        z.z = fmaf(sn.z, dl.z + JITTER, mm.z);
        z.w = fmaf(sn.w, dl.w + JITTER, mm.w);
        out4[i] = z;
    }
}

extern "C" void kernel_launch(void* const* d_in, const int* in_sizes, int n_in,
                              void* d_out, int out_size, void* d_ws, size_t ws_size,
                              hipStream_t stream) {
    const float* m = (const float*)d_in[0];
    const float* diag_L = (const float*)d_in[1];
    const float* std_normal = (const float*)d_in[2];
    float* out = (float*)d_out;

    long long n4_total = (long long)out_size / 4;  // 4096*16384/4 = 16,777,216

    const int block = 256;
    const int grid = 2048;  // 256 CUs × 8 blocks/CU; grid-stride covers the rest

    diag_variational_kernel<<<grid, block, 0, stream>>>(m, diag_L, std_normal, out, n4_total);
}